// Round 7
// baseline (200.888 us; speedup 1.0000x reference)
//
#include <hip/hip_runtime.h>
#include <math.h>

#define HWP 4096
#define CCH 256
#define NN  1024
#define DD  256
#define ZQ_SIZE (8 * DD * HWP)       // 8388608 floats
#define MARGIN 2e-3f                 // 2-product screening: gap-err std 1.3e-4 -> 15 sigma
#define WLCAP 4096
#define NCH 8                        // fixup n-chunks (128 rows each)
#define PXB 8                        // fixup pixels per group

typedef _Float16 h8 __attribute__((ext_vector_type(8)));
typedef float    f4 __attribute__((ext_vector_type(4)));

// ---------- K1: w -> fp16 (hi only), SWIZZLED fragment order + ws zero-init ----------
// whS: [r16 0..63][kc 0..7][lane 0..63][j 0..7] halfs.
__global__ __launch_bounds__(256) void split_w_k(
    const float* __restrict__ w, _Float16* __restrict__ whS,
    int* __restrict__ wcount, unsigned long long* __restrict__ fin,
    int* __restrict__ pgdone)
{
    const int t = blockIdx.x * 256 + threadIdx.x;
    if (t == 0) *wcount = 0;
    if (t < WLCAP) fin[t] = 0ULL;
    if (t < 512)  pgdone[t] = 0;
    const int l = t & 63;
    const int frag = t >> 6;
    const int kc = frag & 7, r16 = frag >> 3;
    const int row = r16 * 16 + (l & 15);
    const int c   = kc * 32 + (l >> 4) * 8;
    const float* src = w + (size_t)row * CCH + c;
    _Float16 hv[8];
#pragma unroll
    for (int j = 0; j < 8; ++j) hv[j] = (_Float16)src[j];
    *(h8*)(whS + (size_t)t * 8) = *(const h8*)hv;
}

// ---------- K2: fused z-split + 2-product MFMA GEMM + top2 + gather ----------
// VERBATIM R6 (proven 62.2 us, VGPR 56, spill-free, absmax 0).
__global__ __launch_bounds__(512, 4) void mfma_gemm_k(
    const float* __restrict__ z,
    const _Float16* __restrict__ whS,
    const float* __restrict__ bias, const float* __restrict__ embed,
    int* __restrict__ wcount, int* __restrict__ wlist,
    float* __restrict__ out)
{
    __shared__ __align__(16) char smem[71680];
    __shared__ int indsh2[64];
    float* s_best = (float*)(smem + 65536);     // [8][64]
    float* s_sec  = (float*)(smem + 67584);
    int*   s_idx  = (int*)  (smem + 69632);

    const int tid = threadIdx.x;
    const int l   = tid & 63;
    const int wv  = tid >> 6;                   // 0..7
    const int mh  = wv >> 2;                    // pixel half: px in [32*mh, 32*mh+32)
    const int ng  = wv & 3;                     // n-group
    const int c15 = l & 15, g = l >> 4;
    const int pix0 = blockIdx.x * 64;
    const int b = pix0 >> 12, p0 = pix0 & 4095;

    // ---- Stage A: z -> hi/lo fp16 frag-order LDS ----
    {
        const int px = tid & 63;
        const int wv2 = tid >> 6;                // 0..7
        const int p16 = px >> 4;
        const float* zb = z + (size_t)b * CCH * HWP + p0 + px;
#pragma unroll
        for (int it = 0; it < 4; ++it) {
            const int cg = wv2 * 4 + it;         // c-group of 8 (0..31)
            const int c = cg * 8;
            float xv[8];
#pragma unroll
            for (int i = 0; i < 8; ++i) xv[i] = zb[(size_t)(c + i) * HWP];
            _Float16 hv[8], lv[8];
#pragma unroll
            for (int i = 0; i < 8; ++i) {
                const _Float16 h = (_Float16)xv[i];
                hv[i] = h;
                lv[i] = (_Float16)(xv[i] - (float)h);
            }
            const int kc = cg >> 2;
            const int lane = (px & 15) + 16 * (cg & 3);
            const int off = ((p16 * 8 + kc) * 64 + lane) * 16;   // bytes, < 32768
            *(h8*)(smem + off)         = *(const h8*)hv;
            *(h8*)(smem + 32768 + off) = *(const h8*)lv;
        }
    }
    __syncthreads();

    float best[8], sec[8]; int bidx[8];
#pragma unroll
    for (int s = 0; s < 8; ++s) { best[s] = -INFINITY; sec[s] = -INFINITY; bidx[s] = 0; }

#pragma unroll 1
    for (int nt = 0; nt < 4; ++nt) {
        const int n0 = nt * 256 + ng * 64;
        const int r16_0 = n0 >> 4;
        f4 acc[2][4];
#pragma unroll
        for (int mf = 0; mf < 2; ++mf)
#pragma unroll
            for (int nf = 0; nf < 4; ++nf) acc[mf][nf] = (f4)0.f;

#pragma unroll 2
        for (int kc = 0; kc < 8; ++kc) {
            h8 ah[2], al[2], bh[4];
#pragma unroll
            for (int mf = 0; mf < 2; ++mf) {
                const int ao = (((mh * 2 + mf) * 8 + kc) * 64 + l) * 16;
                ah[mf] = *(const h8*)(smem + ao);
                al[mf] = *(const h8*)(smem + 32768 + ao);
            }
#pragma unroll
            for (int nf = 0; nf < 4; ++nf) {
                const size_t bo = (((size_t)(r16_0 + nf) * 8 + kc) * 64 + l) * 8;
                bh[nf] = *(const h8*)(whS + bo);
            }
#pragma unroll
            for (int mf = 0; mf < 2; ++mf)
#pragma unroll
                for (int nf = 0; nf < 4; ++nf) {
                    acc[mf][nf] = __builtin_amdgcn_mfma_f32_16x16x32_f16(ah[mf], bh[nf], acc[mf][nf], 0, 0, 0);
                    acc[mf][nf] = __builtin_amdgcn_mfma_f32_16x16x32_f16(al[mf], bh[nf], acc[mf][nf], 0, 0, 0);
                }
        }
#pragma unroll
        for (int nf = 0; nf < 4; ++nf) {
            const int n_abs = n0 + nf * 16 + c15;
            const float bv = bias[n_abs];
#pragma unroll
            for (int mf = 0; mf < 2; ++mf)
#pragma unroll
                for (int r = 0; r < 4; ++r) {
                    const float v = acc[mf][nf][r] + bv;
                    const int s = mf * 4 + r;
                    if (v > best[s]) { sec[s] = best[s]; best[s] = v; bidx[s] = n_abs; }
                    else if (v > sec[s]) sec[s] = v;
                }
        }
    }

#pragma unroll
    for (int d = 1; d < 16; d <<= 1) {
#pragma unroll
        for (int s = 0; s < 8; ++s) {
            const float ob = __shfl_xor(best[s], d, 64);
            const float os = __shfl_xor(sec[s], d, 64);
            const int   oi = __shfl_xor(bidx[s], d, 64);
            if (ob > best[s])       { sec[s] = fmaxf(best[s], os); best[s] = ob; bidx[s] = oi; }
            else if (ob == best[s]) { sec[s] = ob; bidx[s] = (oi < bidx[s]) ? oi : bidx[s]; }
            else                    { sec[s] = fmaxf(sec[s], ob); }
        }
    }
#pragma unroll
    for (int s = 0; s < 8; ++s) {
        if (c15 == s) {
            const int px = (mh * 2 + (s >> 2)) * 16 + g * 4 + (s & 3);
            s_best[wv * 64 + px] = best[s];
            s_sec [wv * 64 + px] = sec[s];
            s_idx [wv * 64 + px] = bidx[s];
        }
    }
    __syncthreads();
    if (tid < 64) {
        const int wb = (tid >> 5) * 4;
        float b0 = s_best[wb * 64 + tid], s0 = s_sec[wb * 64 + tid]; int i0 = s_idx[wb * 64 + tid];
#pragma unroll
        for (int c = 1; c < 4; ++c) {
            const float ob = s_best[(wb + c) * 64 + tid], os = s_sec[(wb + c) * 64 + tid];
            const int   oi = s_idx [(wb + c) * 64 + tid];
            if (ob > b0 || (ob == b0 && oi < i0)) { s0 = fmaxf(b0, os); b0 = ob; i0 = oi; }
            else                                  { s0 = fmaxf(s0, ob); }
        }
        const int pix = pix0 + tid;
        indsh2[tid] = i0;
        out[ZQ_SIZE + 1 + pix] = (float)i0;
        if (b0 - s0 < MARGIN) {
            const int pos = atomicAdd(wcount, 1);
            if (pos < WLCAP) wlist[pos] = pix;
        }
    }
    if (blockIdx.x == 0 && tid == 0) out[ZQ_SIZE] = 0.0f;
    __syncthreads();

    float (*tile)[257] = (float (*)[257])smem;
    const int lq = tid & 63, wq = tid >> 6;
    const int l32 = tid & 31, dq = tid >> 5;
#pragma unroll 1
    for (int pp = 0; pp < 2; ++pp) {
#pragma unroll
        for (int it = 0; it < 4; ++it) {
            const int pl = it * 8 + wq;
            const int row = indsh2[pp * 32 + pl];
            const float4 e = *(const float4*)(embed + (size_t)row * DD + lq * 4);
            tile[pl][lq * 4 + 0] = e.x;
            tile[pl][lq * 4 + 1] = e.y;
            tile[pl][lq * 4 + 2] = e.z;
            tile[pl][lq * 4 + 3] = e.w;
        }
        __syncthreads();
        float* outz = out + (size_t)b * DD * HWP + p0 + pp * 32;
#pragma unroll
        for (int dd = 0; dd < 16; ++dd) {
            const int d = dd * 16 + dq;
            outz[(size_t)d * HWP + l32] = tile[l32][d];
        }
        __syncthreads();
    }
}

// ---------- K3: exact-fp32 fixup, CHUNKED (px-group x n-chunk tasks) ----------
// R6 found fixup wall = ONE block's serial 1 MB w-stream (~17 GB/s latency-
// bound -> 59 us, independent of wcount). Split: task = (pg, ck); 8 px share
// a 128-row chunk stream (128 KB/block, ~8x less serial latency, ~8x more
// concurrent blocks). Cross-chunk combine via device-scope atomicMax on
// encoded u64 (monotone-float-key<<32 | ~idx => max val, min idx). Last
// chunk-block per pg (threadfence+counter, canonical pattern) decodes and
// writes ind + z_q.
__global__ __launch_bounds__(256) void fixup_k(
    const float* __restrict__ z, const float* __restrict__ w,
    const float* __restrict__ bias, const float* __restrict__ embed,
    const int* __restrict__ wcount, const int* __restrict__ wlist,
    unsigned long long* __restrict__ fin, int* __restrict__ pgdone,
    float* __restrict__ out)
{
    __shared__ float zsh[PXB][256];
    __shared__ float m_v[4][PXB];
    __shared__ int   m_i[4][PXB];
    __shared__ int   s_idx[PXB];
    __shared__ int   s_fin;

    const int tid = threadIdx.x;
    const int l = tid & 63, wv = tid >> 6;
    const int c15 = l & 15, q = l >> 4;
    int nw = *wcount;
    if (nw > WLCAP) nw = WLCAP;
    if (nw < 0) nw = 0;
    const int npg = (nw + PXB - 1) / PXB;
    const int ntask = npg * NCH;

    for (int t = blockIdx.x; t < ntask; t += 1024) {
        const int pg = t >> 3, ck = t & 7;
        const int e0 = pg * PXB;
        const int npx = (nw - e0 < PXB) ? (nw - e0) : PXB;
        int pixv[PXB];
#pragma unroll
        for (int px = 0; px < PXB; ++px)
            pixv[px] = wlist[e0 + ((px < npx) ? px : (npx - 1))];

        __syncthreads();   // protect zsh/s_fin reuse across t-iterations
#pragma unroll
        for (int px = 0; px < PXB; ++px) {
            const int pix = pixv[px];
            const int b = pix >> 12, p = pix & 4095;
            zsh[px][tid] = z[((size_t)b * CCH + tid) * HWP + p];
        }
        __syncthreads();

        float best[PXB]; int bi[PXB];
#pragma unroll
        for (int px = 0; px < PXB; ++px) { best[px] = -INFINITY; bi[px] = 0; }

#pragma unroll
        for (int g16 = 0; g16 < 2; ++g16) {
            const int row = ck * 128 + wv * 32 + g16 * 16 + c15;
            const float* wr = w + (size_t)row * CCH + q * 64;
            float part[PXB];
#pragma unroll
            for (int px = 0; px < PXB; ++px) part[px] = 0.f;
#pragma unroll
            for (int j = 0; j < 16; ++j) {
                const float4 w4 = *(const float4*)(wr + j * 4);
#pragma unroll
                for (int px = 0; px < PXB; ++px) {
                    const float4 z4 = *(const float4*)&zsh[px][q * 64 + j * 4];
                    part[px] = fmaf(w4.x, z4.x, part[px]);
                    part[px] = fmaf(w4.y, z4.y, part[px]);
                    part[px] = fmaf(w4.z, z4.z, part[px]);
                    part[px] = fmaf(w4.w, z4.w, part[px]);
                }
            }
            const float bv = bias[row];
#pragma unroll
            for (int px = 0; px < PXB; ++px) {
                float pv = part[px];
                pv += __shfl_xor(pv, 16, 64);
                pv += __shfl_xor(pv, 32, 64);
                const float v = pv + bv;
                if (v > best[px]) { best[px] = v; bi[px] = row; }   // row ascends -> first-min kept
            }
        }
#pragma unroll
        for (int d = 1; d < 16; d <<= 1) {
#pragma unroll
            for (int px = 0; px < PXB; ++px) {
                const float ob = __shfl_xor(best[px], d, 64);
                const int   oi = __shfl_xor(bi[px], d, 64);
                if (ob > best[px] || (ob == best[px] && oi < bi[px])) { best[px] = ob; bi[px] = oi; }
            }
        }
        if (l == 0) {
#pragma unroll
            for (int px = 0; px < PXB; ++px) { m_v[wv][px] = best[px]; m_i[wv][px] = bi[px]; }
        }
        __syncthreads();
        // chunk-best per px -> encoded atomicMax into fin[e]
        if (tid < npx) {
            float v = m_v[0][tid]; int i = m_i[0][tid];
#pragma unroll
            for (int t2 = 1; t2 < 4; ++t2)
                if (m_v[t2][tid] > v || (m_v[t2][tid] == v && m_i[t2][tid] < i)) { v = m_v[t2][tid]; i = m_i[t2][tid]; }
            const unsigned int s = __float_as_uint(v);
            const unsigned int key = (s & 0x80000000u) ? ~s : (s | 0x80000000u);
            const unsigned long long enc =
                ((unsigned long long)key << 32) | (unsigned long long)(~(unsigned int)i);
            atomicMax(&fin[e0 + tid], enc);
        }
        __syncthreads();
        if (tid == 0) {
            __threadfence();
            const int old = atomicAdd(&pgdone[pg], 1);
            s_fin = (old == NCH - 1) ? 1 : 0;
        }
        __syncthreads();
        if (s_fin) {
            if (tid < npx) {
                const unsigned long long cur = atomicMax(&fin[e0 + tid], 0ULL);  // atomic read
                const int idx = (int)(~(unsigned int)cur);
                s_idx[tid] = idx;
                out[ZQ_SIZE + 1 + pixv[tid]] = (float)idx;
            }
            __syncthreads();
            for (int px = 0; px < npx; ++px) {
                const int pix = pixv[px];
                const int b = pix >> 12, p = pix & 4095;
                out[((size_t)b * DD + tid) * HWP + p] = embed[(size_t)s_idx[px] * DD + tid];
            }
        }
    }
}

extern "C" void kernel_launch(void* const* d_in, const int* in_sizes, int n_in,
                              void* d_out, int out_size, void* d_ws, size_t ws_size,
                              hipStream_t stream) {
    const float* z     = (const float*)d_in[0];
    const float* w     = (const float*)d_in[1];
    const float* bias  = (const float*)d_in[2];
    const float* embed = (const float*)d_in[3];
    float* out = (float*)d_out;

    // ws: whS 512K | wcount 256B | wlist 16K | fin 32K | pgdone 2K  (~562 KB, within proven budget)
    _Float16* whS = (_Float16*)d_ws;
    int* wcount = (int*)((char*)d_ws + 524288);
    int* wlist  = (int*)((char*)d_ws + 524544);
    unsigned long long* fin = (unsigned long long*)((char*)d_ws + 540928);
    int* pgdone = (int*)((char*)d_ws + 573696);

    hipLaunchKernelGGL(split_w_k,   dim3(128), dim3(256), 0, stream, w, whS, wcount, fin, pgdone);
    hipLaunchKernelGGL(mfma_gemm_k, dim3(512), dim3(512), 0, stream,
                       z, whS, bias, embed, wcount, wlist, out);
    hipLaunchKernelGGL(fixup_k,     dim3(1024), dim3(256), 0, stream,
                       z, w, bias, embed, wcount, wlist, fin, pgdone, out);
}